// Round 2
// baseline (873.382 us; speedup 1.0000x reference)
//
#include <hip/hip_runtime.h>

// ---------------------------------------------------------------------------
// QGroupLinear: y[m,n] = sum_k x[m,k] * (qw[n,k] * sw[n, k/G]) + bias[n]
// M=4096 (B*S), K=4096, N=11008, G=128.
// R5: fix the R4 pipeline: fragment reads issued ONE PHASE before their
//     consuming MFMA; NO explicit lgkmcnt(0) (compiler emits fine-grained
//     waits) -> read latency hides under previous MFMA cluster. Counted
//     vmcnt(6) once per K-tile (drains tile T+1's 8 loads, keeps T+2's 6
//     in flight). Stage ledger per tile T: P0:B(T+1)h1 -> buf^1;
//     P2:A(T+2)h0, P3:A(T+2)h1+B(T+2)h0 -> buf (same-buf writes land >=2
//     phases after last read-issue of that region). Read schedule:
//     P0: a0[4..7]+a1[0..7] (12), P1: b1 (4), P3(post-ckpt): next tile's
//     a0[0..3]+b0 (8). Every MFMA's operands read >=1 phase earlier.
// R5b: prep split into 2 branch-free kernels (x-convert, w-dequant).
// R4 carry: XOR chunk swizzle (conflicts 0), XCD-aware block swizzle,
//     256x256 tile, BK=64, 8 waves, 128 KiB LDS dbuf, setprio on MFMA.
// ---------------------------------------------------------------------------

typedef __attribute__((ext_vector_type(8))) short short8;
typedef __attribute__((ext_vector_type(4))) float floatx4;

__device__ __forceinline__ unsigned short f2bf_rne(float f) {
  union { float f; unsigned int u; } c;
  c.f = f;
  unsigned int u = c.u;
  u += 0x7FFFu + ((u >> 16) & 1u);   // round-to-nearest-even
  return (unsigned short)(u >> 16);
}

// ---- prep A: xb = bf16(x), 8 elems per chunk, grid-stride ----------------
__global__ void prep_x_kernel(const float* __restrict__ x,
                              short* __restrict__ xb, long nchunks) {
  long stride = (long)gridDim.x * blockDim.x;
  for (long c = (long)blockIdx.x * blockDim.x + threadIdx.x;
       c < nchunks; c += stride) {
    const float4* p = (const float4*)(x + c * 8);
    float4 a = p[0], b = p[1];
    short8 o;
    o[0] = (short)f2bf_rne(a.x); o[1] = (short)f2bf_rne(a.y);
    o[2] = (short)f2bf_rne(a.z); o[3] = (short)f2bf_rne(a.w);
    o[4] = (short)f2bf_rne(b.x); o[5] = (short)f2bf_rne(b.y);
    o[6] = (short)f2bf_rne(b.z); o[7] = (short)f2bf_rne(b.w);
    *(short8*)(xb + c * 8) = o;
  }
}

// ---- prep B: wb = bf16(qw * sw), 8 elems per chunk, grid-stride ----------
__global__ void prep_w_kernel(const int* __restrict__ qw,
                              const float* __restrict__ sw,
                              short* __restrict__ wb, long nchunks,
                              int kc, int kcshift, int gc, int gcshift,
                              int ngroups) {
  long stride = (long)gridDim.x * blockDim.x;
  for (long c = (long)blockIdx.x * blockDim.x + threadIdx.x;
       c < nchunks; c += stride) {
    int n, kch;
    if (kcshift >= 0) {
      n = (int)(c >> kcshift);
      kch = (int)(c & (long)(kc - 1));
    } else {
      n = (int)(c / kc);
      kch = (int)(c - (long)n * kc);
    }
    int g = (gcshift >= 0) ? (kch >> gcshift) : (kch / gc);
    float s = sw[(long)n * ngroups + g];
    const int* q = qw + c * 8;
    int4 q0 = *(const int4*)q;
    int4 q1 = *(const int4*)(q + 4);
    short8 o;
    o[0] = (short)f2bf_rne((float)q0.x * s);
    o[1] = (short)f2bf_rne((float)q0.y * s);
    o[2] = (short)f2bf_rne((float)q0.z * s);
    o[3] = (short)f2bf_rne((float)q0.w * s);
    o[4] = (short)f2bf_rne((float)q1.x * s);
    o[5] = (short)f2bf_rne((float)q1.y * s);
    o[6] = (short)f2bf_rne((float)q1.z * s);
    o[7] = (short)f2bf_rne((float)q1.w * s);
    *(short8*)(wb + c * 8) = o;
  }
}

// ---- 8-phase 256x256 bf16 MFMA GEMM: Y = Xb * Wb^T + bias -----------------
#define BM 256
#define BN 256
#define BK 64

// Stage one 128-row x 64-col (bf16) half-tile into LDS via global_load_lds.
// LDS dest is linear (HW: wave-uniform base + lane*16); the XOR swizzle
// (chunk ^= row&7) is applied by pre-swizzling the GLOBAL source column.
__device__ __forceinline__ void stage_half(const short* __restrict__ src,
                                           int rowbase, int k0, int K,
                                           short* dst, int t) {
#pragma unroll
  for (int j = 0; j < 2; ++j) {
    const int c = (j << 9) | t;          // 0..1023 chunk id (16B chunks)
    const int r = c >> 3;                // row 0..127
    const int g = (c & 7) ^ (r & 7);     // global k-chunk for this slot
    __builtin_amdgcn_global_load_lds(
        (const __attribute__((address_space(1))) void*)(
            src + (long)(rowbase + r) * K + k0 + (g << 3)),
        (__attribute__((address_space(3))) void*)(dst + (c << 3)),
        16, 0, 0);
  }
}

__global__ __launch_bounds__(512, 2) void gemm8p_kernel(
    const short* __restrict__ Xb,    // [M][K] bf16 bits
    const short* __restrict__ Wb,    // [N][K] bf16 bits
    const float* __restrict__ bias,  // [N]
    float* __restrict__ Y,           // [M][N]
    int M, int N, int K) {
  // [buf][half][row*64 + swizzled-chunk*8] ; 64 KB + 64 KB = 128 KiB
  __shared__ short As[2][2][128 * 64];
  __shared__ short Bs[2][2][128 * 64];

  const int t = threadIdx.x;       // 0..511
  const int wave = t >> 6;         // 0..7
  const int lane = t & 63;
  const int wm = wave >> 2;        // 0..1  (A half / M 128-stripe)
  const int wn = wave & 3;         // 0..3  (N 64-stripe)
  const int quad = lane >> 4;      // 0..3
  const int l16 = lane & 15;

  // ---- XCD-aware swizzle: xcd owns an M-stripe, sweeps N with M-interleave
  const int gm = M / BM, gn = N / BN;
  int bid = (int)blockIdx.x;
  int mt, nt;
  if ((gm & 7) == 0) {
    int stripe = gm >> 3;
    int xcd = bid & 7;
    int q = bid >> 3;
    mt = xcd * stripe + q % stripe;
    nt = q / stripe;
  } else {
    mt = bid % gm;
    nt = bid / gm;
  }
  const long tileM = (long)mt * BM;
  const long tileN = (long)nt * BN;

  const short* __restrict__ Ag = Xb + tileM * K;
  const short* __restrict__ Bg = Wb + tileN * K;

  floatx4 acc[8][4];
#pragma unroll
  for (int i = 0; i < 8; ++i)
#pragma unroll
    for (int j = 0; j < 4; ++j) acc[i][j] = {0.f, 0.f, 0.f, 0.f};

  const int NT = K / BK;   // >= 2 guaranteed by launcher

  // ---- prologue: tile0 (4 halves) + tile1 {Ah0, Ah1, Bh0} = 14 loads.
  // vmcnt(6): tile0 resident, tile1's 3 halves (6 loads) stay in flight.
  stage_half(Ag,   0,  0, K, &As[0][0][0], t);
  stage_half(Ag, 128,  0, K, &As[0][1][0], t);
  stage_half(Bg,   0,  0, K, &Bs[0][0][0], t);
  stage_half(Bg, 128,  0, K, &Bs[0][1][0], t);
  stage_half(Ag,   0, BK, K, &As[1][0][0], t);
  stage_half(Ag, 128, BK, K, &As[1][1][0], t);
  stage_half(Bg,   0, BK, K, &Bs[1][0][0], t);
  asm volatile("s_waitcnt vmcnt(6)" ::: "memory");
  __builtin_amdgcn_s_barrier();
  asm volatile("" ::: "memory");
  __builtin_amdgcn_sched_barrier(0);

  // fragment read offsets: global chunk (ks*4 + quad) at row r -> physical
  // chunk ^= (r&7); frag row = i*16+l16 -> ^(l16&7). ks1 offset = ^32 shorts.
  const int c0 = (quad ^ (l16 & 7)) << 3;   // shorts
  const int c1 = c0 ^ 32;
  const int nb = (wn & 1) * 64;             // n-row base inside B half

  short8 a0[8], a1[8], b0[4], b1[4];
  {  // initial: a0[0..3], b0 of tile 0 (the steady-state P3 read)
    const short* Ab = &As[0][wm][0];
    const short* Bb = &Bs[0][wn >> 1][0];
#pragma unroll
    for (int i = 0; i < 4; ++i)
      a0[i] = *(const short8*)(Ab + (i * 16 + l16) * 64 + c0);
#pragma unroll
    for (int j = 0; j < 4; ++j)
      b0[j] = *(const short8*)(Bb + (nb + j * 16 + l16) * 64 + c0);
  }

  for (int T = 0; T < NT; ++T) {
    const int buf = T & 1;
    const short* Ab  = &As[buf][wm][0];
    const short* Bb  = &Bs[buf][wn >> 1][0];
    const short* Abn = &As[buf ^ 1][wm][0];
    const short* Bbn = &Bs[buf ^ 1][wn >> 1][0];

    // ==== P0: stage B(T+1)h1 -> buf^1 | read a0[4..7](c0), a1[0..7](c1)
    //          | MFMA a0[0..3] x b0 (operands read last tile's P3)
    if (T + 1 < NT)
      stage_half(Bg, 128, (T + 1) * BK, K, &Bs[buf ^ 1][1][0], t);
#pragma unroll
    for (int i = 0; i < 4; ++i)
      a0[4 + i] = *(const short8*)(Ab + ((4 + i) * 16 + l16) * 64 + c0);
#pragma unroll
    for (int i = 0; i < 8; ++i)
      a1[i] = *(const short8*)(Ab + (i * 16 + l16) * 64 + c1);
    __builtin_amdgcn_s_barrier();
    __builtin_amdgcn_s_setprio(1);
#pragma unroll
    for (int i = 0; i < 4; ++i)
#pragma unroll
      for (int j = 0; j < 4; ++j)
        acc[i][j] = __builtin_amdgcn_mfma_f32_16x16x32_bf16(a0[i], b0[j],
                                                            acc[i][j], 0, 0, 0);
    __builtin_amdgcn_s_setprio(0);
    __builtin_amdgcn_s_barrier();

    // ==== P1: read b1(c1) | MFMA a0[4..7] x b0 (a0[4..7] read P0)
#pragma unroll
    for (int j = 0; j < 4; ++j)
      b1[j] = *(const short8*)(Bb + (nb + j * 16 + l16) * 64 + c1);
    __builtin_amdgcn_s_barrier();
    __builtin_amdgcn_s_setprio(1);
#pragma unroll
    for (int i = 0; i < 4; ++i)
#pragma unroll
      for (int j = 0; j < 4; ++j)
        acc[4 + i][j] = __builtin_amdgcn_mfma_f32_16x16x32_bf16(
            a0[4 + i], b0[j], acc[4 + i][j], 0, 0, 0);
    __builtin_amdgcn_s_setprio(0);
    __builtin_amdgcn_s_barrier();

    // ==== P2: stage A(T+2)h0 -> buf (reads of As[buf] all issued at P0,
    //          executed >=1 phase before this write can land)
    //          | MFMA a1[0..3] x b1 (a1 read P0, b1 read P1)
    if (T + 2 < NT)
      stage_half(Ag, 0, (T + 2) * BK, K, &As[buf][0][0], t);
    __builtin_amdgcn_s_barrier();
    __builtin_amdgcn_s_setprio(1);
#pragma unroll
    for (int i = 0; i < 4; ++i)
#pragma unroll
      for (int j = 0; j < 4; ++j)
        acc[i][j] = __builtin_amdgcn_mfma_f32_16x16x32_bf16(a1[i], b1[j],
                                                            acc[i][j], 0, 0, 0);
    __builtin_amdgcn_s_setprio(0);
    __builtin_amdgcn_s_barrier();

    // ==== P3: stage A(T+2)h1 + B(T+2)h0 -> buf | vmcnt ckpt | barrier |
    //          read next tile's a0[0..3], b0 from buf^1 | MFMA a1[4..7] x b1
    if (T + 2 < NT) {
      stage_half(Ag, 128, (T + 2) * BK, K, &As[buf][1][0], t);
      stage_half(Bg, 0, (T + 2) * BK, K, &Bs[buf][0][0], t);
      // outstanding: A(T+1)h0,h1,B(T+1)h0 (6 from earlier) + B(T+1)h1 (P0)
      // + A(T+2)h0 (P2) + A(T+2)h1,B(T+2)h0 (P3) = 14. Drain 8 oldest
      // -> tile T+1 fully resident; keep T+2's 6 in flight.
      asm volatile("s_waitcnt vmcnt(6)" ::: "memory");
    } else {
      asm volatile("s_waitcnt vmcnt(0)" ::: "memory");
    }
    __builtin_amdgcn_s_barrier();
    asm volatile("" ::: "memory");
    __builtin_amdgcn_sched_barrier(0);
    if (T + 1 < NT) {
#pragma unroll
      for (int i = 0; i < 4; ++i)
        a0[i] = *(const short8*)(Abn + (i * 16 + l16) * 64 + c0);
#pragma unroll
      for (int j = 0; j < 4; ++j)
        b0[j] = *(const short8*)(Bbn + (nb + j * 16 + l16) * 64 + c0);
    }
    __builtin_amdgcn_s_setprio(1);
#pragma unroll
    for (int i = 0; i < 4; ++i)
#pragma unroll
      for (int j = 0; j < 4; ++j)
        acc[4 + i][j] = __builtin_amdgcn_mfma_f32_16x16x32_bf16(
            a1[4 + i], b1[j], acc[4 + i][j], 0, 0, 0);
    __builtin_amdgcn_s_setprio(0);
    __builtin_amdgcn_s_barrier();
  }

  // ---- epilogue: C/D layout col = l16 (n), row = quad*4 + reg (m) ---------
  const long mbase = tileM + wm * 128;
  const long nbase = tileN + wn * 64;
#pragma unroll
  for (int j = 0; j < 4; ++j) {
    const long n = nbase + j * 16 + l16;
    const float bv = bias[n];
#pragma unroll
    for (int i = 0; i < 8; ++i) {
      const long m0 = mbase + i * 16 + quad * 4;
#pragma unroll
      for (int r = 0; r < 4; ++r)
        Y[(m0 + r) * (long)N + n] = acc[i][j][r] + bv;
    }
  }
}

// ---- fallback (only if ws too small / odd shapes): correct but slow -------
__global__ void naive_kernel(const float* __restrict__ x,
                             const int* __restrict__ qw,
                             const float* __restrict__ sw,
                             const float* __restrict__ bias,
                             float* __restrict__ y,
                             int M, int N, int K, int G) {
  long idx = (long)blockIdx.x * blockDim.x + threadIdx.x;
  if (idx >= (long)M * N) return;
  int m = (int)(idx / N), n = (int)(idx % N);
  int ng = K / G;
  float acc = 0.f;
  for (int g = 0; g < ng; g++) {
    float s = sw[(long)n * ng + g];
    float part = 0.f;
    for (int k = g * G; k < (g + 1) * G; k++)
      part += x[(long)m * K + k] * (float)qw[(long)n * K + k];
    acc += part * s;
  }
  y[idx] = acc + bias[n];
}

extern "C" void kernel_launch(void* const* d_in, const int* in_sizes, int n_in,
                              void* d_out, int out_size, void* d_ws, size_t ws_size,
                              hipStream_t stream) {
  const float* x = (const float*)d_in[0];
  const int* qw = (const int*)d_in[1];
  const float* sw = (const float*)d_in[2];
  const float* bias = (const float*)d_in[3];
  float* y = (float*)d_out;

  const int N = in_sizes[3];
  const int K = in_sizes[1] / N;
  const int M = in_sizes[0] / K;
  const int ngroups = in_sizes[2] / N;
  const int G = K / ngroups;

  const long MK = (long)M * K;
  const long NK = (long)N * K;
  const size_t need = (size_t)(MK + NK) * sizeof(short);

  if (ws_size < need || (M % BM) || (N % BN) || (K % BK) || (K < 2 * BK) ||
      (G % 8)) {
    long total = (long)M * N;
    naive_kernel<<<(unsigned)((total + 255) / 256), 256, 0, stream>>>(
        x, qw, sw, bias, y, M, N, K, G);
    return;
  }

  short* xb = (short*)d_ws;
  short* wb = xb + MK;

  const int kc = K / 8;        // chunks per row
  const int gc = G / 8;        // chunks per group
  int kcshift = ((kc & (kc - 1)) == 0) ? __builtin_ctz((unsigned)kc) : -1;
  int gcshift = ((gc & (gc - 1)) == 0) ? __builtin_ctz((unsigned)gc) : -1;

  prep_x_kernel<<<2048, 256, 0, stream>>>(x, xb, MK / 8);
  prep_w_kernel<<<2048, 256, 0, stream>>>(qw, sw, wb, NK / 8,
                                          kc, kcshift, gc, gcshift, ngroups);

  dim3 grid((unsigned)((M / BM) * (N / BN)));
  gemm8p_kernel<<<grid, 512, 0, stream>>>(xb, wb, bias, y, M, N, K);
}

// Round 3
// 741.168 us; speedup vs baseline: 1.1784x; 1.1784x over previous
//
#include <hip/hip_runtime.h>

// ---------------------------------------------------------------------------
// QGroupLinear: y[m,n] = sum_k x[m,k] * (qw[n,k] * sw[n, k/G]) + bias[n]
// M=4096 (B*S), K=4096, N=11008, G=128.
// R6: revert to proven R3 GEMM structure (128x128 tile, BK=32, 4 waves,
//     4 blocks/CU, XOR chunk swizzle, XCD-aware block swizzle) + ONE change:
//     minimum-2-phase double buffering (catalog T3-minimum recipe):
//       prologue: STAGE(buf0); sync;
//       loop: STAGE(buf^1, next tile) BEFORE ds_read+MFMA of buf;
//             ONE __syncthreads() per K-step (its implicit vmcnt(0) drain is
//             cheap: loads had the whole MFMA phase to land).
//     vs R3: removes one barrier per step and overlaps staging with compute
//     within-wave (R3 exposed full load latency between its two barriers).
//     WAR safety: iter t writes buf^1; all reads of buf^1 were issued and
//     completed (compiler lgkmcnt before MFMA) before iter t-1's barrier.
// R5 carry: split branch-free preps (x-convert, w-dequant).
// Failed & reverted: R4/R5 8-phase 256^2 ports (432 -> 432 / 568 us;
//     fragment live-range blowup + unbalanced LDS phases; see journal).
// ---------------------------------------------------------------------------

typedef __attribute__((ext_vector_type(8))) short short8;
typedef __attribute__((ext_vector_type(4))) float floatx4;

__device__ __forceinline__ unsigned short f2bf_rne(float f) {
  union { float f; unsigned int u; } c;
  c.f = f;
  unsigned int u = c.u;
  u += 0x7FFFu + ((u >> 16) & 1u);   // round-to-nearest-even
  return (unsigned short)(u >> 16);
}

// ---- prep A: xb = bf16(x), 8 elems per chunk, grid-stride ----------------
__global__ void prep_x_kernel(const float* __restrict__ x,
                              short* __restrict__ xb, long nchunks) {
  long stride = (long)gridDim.x * blockDim.x;
  for (long c = (long)blockIdx.x * blockDim.x + threadIdx.x;
       c < nchunks; c += stride) {
    const float4* p = (const float4*)(x + c * 8);
    float4 a = p[0], b = p[1];
    short8 o;
    o[0] = (short)f2bf_rne(a.x); o[1] = (short)f2bf_rne(a.y);
    o[2] = (short)f2bf_rne(a.z); o[3] = (short)f2bf_rne(a.w);
    o[4] = (short)f2bf_rne(b.x); o[5] = (short)f2bf_rne(b.y);
    o[6] = (short)f2bf_rne(b.z); o[7] = (short)f2bf_rne(b.w);
    *(short8*)(xb + c * 8) = o;
  }
}

// ---- prep B: wb = bf16(qw * sw), 8 elems per chunk, grid-stride ----------
__global__ void prep_w_kernel(const int* __restrict__ qw,
                              const float* __restrict__ sw,
                              short* __restrict__ wb, long nchunks,
                              int kc, int kcshift, int gc, int gcshift,
                              int ngroups) {
  long stride = (long)gridDim.x * blockDim.x;
  for (long c = (long)blockIdx.x * blockDim.x + threadIdx.x;
       c < nchunks; c += stride) {
    int n, kch;
    if (kcshift >= 0) {
      n = (int)(c >> kcshift);
      kch = (int)(c & (long)(kc - 1));
    } else {
      n = (int)(c / kc);
      kch = (int)(c - (long)n * kc);
    }
    int g = (gcshift >= 0) ? (kch >> gcshift) : (kch / gc);
    float s = sw[(long)n * ngroups + g];
    const int* q = qw + c * 8;
    int4 q0 = *(const int4*)q;
    int4 q1 = *(const int4*)(q + 4);
    short8 o;
    o[0] = (short)f2bf_rne((float)q0.x * s);
    o[1] = (short)f2bf_rne((float)q0.y * s);
    o[2] = (short)f2bf_rne((float)q0.z * s);
    o[3] = (short)f2bf_rne((float)q0.w * s);
    o[4] = (short)f2bf_rne((float)q1.x * s);
    o[5] = (short)f2bf_rne((float)q1.y * s);
    o[6] = (short)f2bf_rne((float)q1.z * s);
    o[7] = (short)f2bf_rne((float)q1.w * s);
    *(short8*)(wb + c * 8) = o;
  }
}

// ---- bf16 MFMA GEMM: Y[M][N] = Xb[M][K] * Wb[N][K]^T + bias ---------------
#define BM 128
#define BN 128
#define BK 32

// LDS layout per buffer: tile rows of BK=32 shorts (4 chunks of 16B).
// Physical chunk (r, cc) holds GLOBAL chunk (r, cc ^ ((r>>1)&3)) ->
// fragment reads are 2-way (free) instead of 8-way bank conflicts.
// Staging fetches the permuted global chunk (same 64B row segment,
// coalescing unchanged). SQ_LDS_BANK_CONFLICT measured 0 with this.

__device__ __forceinline__ void stage_tile(const short* __restrict__ Ag,
                                           const short* __restrict__ Bg,
                                           int k0, int K,
                                           short* Adst, short* Bdst,
                                           int t, int srow, int scol) {
#pragma unroll
  for (int i = 0; i < 2; ++i)
    __builtin_amdgcn_global_load_lds(
        (const __attribute__((address_space(1))) void*)(
            Ag + (long)(i * 64 + srow) * K + k0 + scol),
        (__attribute__((address_space(3))) void*)(Adst + i * 64 * BK + t * 8),
        16, 0, 0);
#pragma unroll
  for (int i = 0; i < 2; ++i)
    __builtin_amdgcn_global_load_lds(
        (const __attribute__((address_space(1))) void*)(
            Bg + (long)(i * 64 + srow) * K + k0 + scol),
        (__attribute__((address_space(3))) void*)(Bdst + i * 64 * BK + t * 8),
        16, 0, 0);
}

__global__ __launch_bounds__(256, 4) void gemm_bt_kernel(
    const short* __restrict__ Xb,    // [M][K] bf16 bits
    const short* __restrict__ Wb,    // [N][K] bf16 bits
    const float* __restrict__ bias,  // [N]
    float* __restrict__ Y,           // [M][N]
    int M, int N, int K) {
  __shared__ short As[2][BM * BK];  // 2 x 8 KB
  __shared__ short Bs[2][BN * BK];  // 2 x 8 KB

  const int t = threadIdx.x;     // 0..255
  const int wave = t >> 6;       // 0..3
  const int lane = t & 63;
  const int wm = wave >> 1;      // 0..1 (m-half)
  const int wn = wave & 1;       // 0..1 (n-half)
  const int quad = lane >> 4;    // 0..3
  const int l16 = lane & 15;

  // ---- XCD-aware swizzle: xcd = bid%8 owns M-tile stripe, sweeps N;
  // consecutive same-XCD blocks share one B panel in that XCD's L2.
  const int gn = gridDim.x, gm = gridDim.y;
  int mt, nt;
  if ((gm & 7) == 0) {
    int stripe = gm >> 3;
    int bid = blockIdx.y * gn + blockIdx.x;
    int xcd = bid & 7;
    int q = bid >> 3;
    int msub = q % stripe;
    nt = q / stripe;
    mt = xcd * stripe + msub;
  } else {
    mt = blockIdx.y; nt = blockIdx.x;
  }
  const int tileM = mt * BM;
  const int tileN = nt * BN;

  floatx4 acc[4][4];
#pragma unroll
  for (int i = 0; i < 4; i++)
#pragma unroll
    for (int j = 0; j < 4; j++) acc[i][j] = {0.f, 0.f, 0.f, 0.f};

  // staging: thread t fills physical chunk t (16B at dst + t*8 shorts);
  // fetches GLOBAL chunk (row = t>>2, col = (t&3) ^ ((t>>3)&3)).
  const int srow = t >> 2;
  const int scol = ((t & 3) ^ ((t >> 3) & 3)) * 8;   // shorts

  const short* Ag = Xb + (long)tileM * K;
  const short* Bg = Wb + (long)tileN * K;

  // fragment read: global chunk q of row r is at physical chunk
  // q ^ ((r>>1)&3); r = i*16+l16 -> q ^ ((l16>>1)&3).
  const int cswz = (quad ^ ((l16 >> 1) & 3)) * 8;    // shorts

  // ---- prologue: stage tile 0 into buf 0 ---------------------------------
  stage_tile(Ag, Bg, 0, K, &As[0][0], &Bs[0][0], t, srow, scol);
  __syncthreads();   // implicit s_waitcnt vmcnt(0) lgkmcnt(0) + s_barrier

  int cur = 0;
  for (int k0 = 0; k0 < K; k0 += BK, cur ^= 1) {
    // 2-phase: issue NEXT tile's loads first -> they land during MFMA,
    // so the barrier's vmcnt(0) drain at the end of this iter is cheap.
    if (k0 + BK < K)
      stage_tile(Ag, Bg, k0 + BK, K, &As[cur ^ 1][0], &Bs[cur ^ 1][0],
                 t, srow, scol);

    const short* Aw = &As[cur][0] + wm * 64 * BK;
    const short* Bw = &Bs[cur][0] + wn * 64 * BK;
    short8 af[4], bf[4];
#pragma unroll
    for (int i = 0; i < 4; i++)
      af[i] = *(const short8*)(Aw + (i * 16 + l16) * BK + cswz);
#pragma unroll
    for (int j = 0; j < 4; j++)
      bf[j] = *(const short8*)(Bw + (j * 16 + l16) * BK + cswz);

#pragma unroll
    for (int i = 0; i < 4; i++)
#pragma unroll
      for (int j = 0; j < 4; j++)
        acc[i][j] = __builtin_amdgcn_mfma_f32_16x16x32_bf16(af[i], bf[j],
                                                            acc[i][j], 0, 0, 0);
    __syncthreads();   // one barrier per K-step (drains vmcnt for next iter)
  }

  // epilogue: C/D layout col=lane&15 (n), row=quad*4+reg (m)
  const int mbase = tileM + wm * 64;
  const int nbase = tileN + wn * 64;
#pragma unroll
  for (int i = 0; i < 4; i++) {
#pragma unroll
    for (int j = 0; j < 4; j++) {
      int n = nbase + j * 16 + l16;
      float bv = bias[n];
#pragma unroll
      for (int r = 0; r < 4; r++) {
        int m = mbase + i * 16 + quad * 4 + r;
        Y[(long)m * N + n] = acc[i][j][r] + bv;
      }
    }
  }
}

// ---- fallback (only if ws too small / odd shapes): correct but slow -------
__global__ void naive_kernel(const float* __restrict__ x,
                             const int* __restrict__ qw,
                             const float* __restrict__ sw,
                             const float* __restrict__ bias,
                             float* __restrict__ y,
                             int M, int N, int K, int G) {
  long idx = (long)blockIdx.x * blockDim.x + threadIdx.x;
  if (idx >= (long)M * N) return;
  int m = (int)(idx / N), n = (int)(idx % N);
  int ng = K / G;
  float acc = 0.f;
  for (int g = 0; g < ng; g++) {
    float s = sw[(long)n * ng + g];
    float part = 0.f;
    for (int k = g * G; k < (g + 1) * G; k++)
      part += x[(long)m * K + k] * (float)qw[(long)n * K + k];
    acc += part * s;
  }
  y[idx] = acc + bias[n];
}

extern "C" void kernel_launch(void* const* d_in, const int* in_sizes, int n_in,
                              void* d_out, int out_size, void* d_ws, size_t ws_size,
                              hipStream_t stream) {
  const float* x = (const float*)d_in[0];
  const int* qw = (const int*)d_in[1];
  const float* sw = (const float*)d_in[2];
  const float* bias = (const float*)d_in[3];
  float* y = (float*)d_out;

  const int N = in_sizes[3];
  const int K = in_sizes[1] / N;
  const int M = in_sizes[0] / K;
  const int ngroups = in_sizes[2] / N;
  const int G = K / ngroups;

  const long MK = (long)M * K;
  const long NK = (long)N * K;
  const size_t need = (size_t)(MK + NK) * sizeof(short);

  if (ws_size < need || (M % BM) || (N % BN) || (K % BK) || (G % 8)) {
    long total = (long)M * N;
    naive_kernel<<<(unsigned)((total + 255) / 256), 256, 0, stream>>>(
        x, qw, sw, bias, y, M, N, K, G);
    return;
  }

  short* xb = (short*)d_ws;
  short* wb = xb + MK;

  const int kc = K / 8;        // chunks per row
  const int gc = G / 8;        // chunks per group
  int kcshift = ((kc & (kc - 1)) == 0) ? __builtin_ctz((unsigned)kc) : -1;
  int gcshift = ((gc & (gc - 1)) == 0) ? __builtin_ctz((unsigned)gc) : -1;

  prep_x_kernel<<<2048, 256, 0, stream>>>(x, xb, MK / 8);
  prep_w_kernel<<<2048, 256, 0, stream>>>(qw, sw, wb, NK / 8,
                                          kc, kcshift, gc, gcshift, ngroups);

  dim3 grid((unsigned)(N / BN), (unsigned)(M / BM));
  gemm_bt_kernel<<<grid, 256, 0, stream>>>(xb, wb, bias, y, M, N, K);
}

// Round 4
// 670.295 us; speedup vs baseline: 1.3030x; 1.1057x over previous
//
#include <hip/hip_runtime.h>

// ---------------------------------------------------------------------------
// QGroupLinear: y[m,n] = sum_k x[m,k] * (qw[n,k] * sw[n, k/G]) + bias[n]
// M=4096 (B*S), K=4096, N=11008, G=128.
// R7: R3's proven two-barrier loop (stage -> sync -> read+MFMA -> sync),
//     ONE variable changed: BK 32 -> 64. Halves barrier/drain events per
//     K-sweep (64 iters instead of 128) while keeping 4 blocks/CU
//     (LDS 32KB single-buffered, VGPR <= 128 via launch_bounds).
//     Swizzle re-derived for 8 chunks/row: physical chunk pc of row r holds
//     global chunk pc ^ (r&7); fragment read offset c0 = (quad^(l16&7))*8,
//     ks1 = c0 ^ 32 -> reads spread all 32 banks (b128 floor), staging
//     still fetches whole 128B rows (coalescing unchanged).
// Failed & reverted (journal): R4/R5 8-phase 256^2 ports (432/568 us),
//     R6 2-phase dbuf (455 us) - all at/below the m97-structure wall.
//     Rejected on arithmetic: i8 MFMA (per-group fixup VALU-bound),
//     MX-fp8 weights (e4m3 error ~1.7 vs 2.0 absmax budget).
// R5 carry: split branch-free preps (x-convert, w-dequant).
// ---------------------------------------------------------------------------

typedef __attribute__((ext_vector_type(8))) short short8;
typedef __attribute__((ext_vector_type(4))) float floatx4;

__device__ __forceinline__ unsigned short f2bf_rne(float f) {
  union { float f; unsigned int u; } c;
  c.f = f;
  unsigned int u = c.u;
  u += 0x7FFFu + ((u >> 16) & 1u);   // round-to-nearest-even
  return (unsigned short)(u >> 16);
}

// ---- prep A: xb = bf16(x), 8 elems per chunk, grid-stride ----------------
__global__ void prep_x_kernel(const float* __restrict__ x,
                              short* __restrict__ xb, long nchunks) {
  long stride = (long)gridDim.x * blockDim.x;
  for (long c = (long)blockIdx.x * blockDim.x + threadIdx.x;
       c < nchunks; c += stride) {
    const float4* p = (const float4*)(x + c * 8);
    float4 a = p[0], b = p[1];
    short8 o;
    o[0] = (short)f2bf_rne(a.x); o[1] = (short)f2bf_rne(a.y);
    o[2] = (short)f2bf_rne(a.z); o[3] = (short)f2bf_rne(a.w);
    o[4] = (short)f2bf_rne(b.x); o[5] = (short)f2bf_rne(b.y);
    o[6] = (short)f2bf_rne(b.z); o[7] = (short)f2bf_rne(b.w);
    *(short8*)(xb + c * 8) = o;
  }
}

// ---- prep B: wb = bf16(qw * sw), 8 elems per chunk, grid-stride ----------
__global__ void prep_w_kernel(const int* __restrict__ qw,
                              const float* __restrict__ sw,
                              short* __restrict__ wb, long nchunks,
                              int kc, int kcshift, int gc, int gcshift,
                              int ngroups) {
  long stride = (long)gridDim.x * blockDim.x;
  for (long c = (long)blockIdx.x * blockDim.x + threadIdx.x;
       c < nchunks; c += stride) {
    int n, kch;
    if (kcshift >= 0) {
      n = (int)(c >> kcshift);
      kch = (int)(c & (long)(kc - 1));
    } else {
      n = (int)(c / kc);
      kch = (int)(c - (long)n * kc);
    }
    int g = (gcshift >= 0) ? (kch >> gcshift) : (kch / gc);
    float s = sw[(long)n * ngroups + g];
    const int* q = qw + c * 8;
    int4 q0 = *(const int4*)q;
    int4 q1 = *(const int4*)(q + 4);
    short8 o;
    o[0] = (short)f2bf_rne((float)q0.x * s);
    o[1] = (short)f2bf_rne((float)q0.y * s);
    o[2] = (short)f2bf_rne((float)q0.z * s);
    o[3] = (short)f2bf_rne((float)q0.w * s);
    o[4] = (short)f2bf_rne((float)q1.x * s);
    o[5] = (short)f2bf_rne((float)q1.y * s);
    o[6] = (short)f2bf_rne((float)q1.z * s);
    o[7] = (short)f2bf_rne((float)q1.w * s);
    *(short8*)(wb + c * 8) = o;
  }
}

// ---- bf16 MFMA GEMM: Y[M][N] = Xb[M][K] * Wb[N][K]^T + bias ---------------
#define BM 128
#define BN 128
#define BK 64

__global__ __launch_bounds__(256, 4) void gemm_bt_kernel(
    const short* __restrict__ Xb,    // [M][K] bf16 bits
    const short* __restrict__ Wb,    // [N][K] bf16 bits
    const float* __restrict__ bias,  // [N]
    float* __restrict__ Y,           // [M][N]
    int M, int N, int K) {
  __shared__ short As[BM * BK];  // 16 KB
  __shared__ short Bs[BN * BK];  // 16 KB

  const int t = threadIdx.x;     // 0..255
  const int wave = t >> 6;       // 0..3
  const int lane = t & 63;
  const int wm = wave >> 1;      // 0..1 (m-half)
  const int wn = wave & 1;       // 0..1 (n-half)
  const int quad = lane >> 4;    // 0..3
  const int l16 = lane & 15;

  // ---- XCD-aware swizzle: xcd = bid%8 owns M-tile stripe, sweeps N;
  // consecutive same-XCD blocks share one B panel in that XCD's L2.
  const int gn = gridDim.x, gm = gridDim.y;
  int mt, nt;
  if ((gm & 7) == 0) {
    int stripe = gm >> 3;
    int bid = blockIdx.y * gn + blockIdx.x;
    int xcd = bid & 7;
    int q = bid >> 3;
    int msub = q % stripe;
    nt = q / stripe;
    mt = xcd * stripe + msub;
  } else {
    mt = blockIdx.y; nt = blockIdx.x;
  }
  const int tileM = mt * BM;
  const int tileN = nt * BN;

  floatx4 acc[4][4];
#pragma unroll
  for (int i = 0; i < 4; i++)
#pragma unroll
    for (int j = 0; j < 4; j++) acc[i][j] = {0.f, 0.f, 0.f, 0.f};

  const short* Ag = Xb + (long)tileM * K;
  const short* Bg = Wb + (long)tileN * K;

  // fragment read: row r = (half)*64 + i*16 + l16, global chunk g = s*4+quad
  // -> physical chunk g ^ (r&7) = g ^ (l16&7). ks1 offset = c0 ^ 32 shorts.
  const int c0 = (quad ^ (l16 & 7)) << 3;    // shorts

  for (int k0 = 0; k0 < K; k0 += BK) {
    // stage: thread t fills physical chunks {t, 256+t, 512+t, 768+t} of each
    // operand; physical (r = c>>3, pc = c&7) holds global chunk pc ^ (r&7).
#pragma unroll
    for (int jj = 0; jj < 4; ++jj) {
      const int c = (jj << 8) | t;
      const int r = c >> 3;
      const int g = (c & 7) ^ (r & 7);
      __builtin_amdgcn_global_load_lds(
          (const __attribute__((address_space(1))) void*)(
              Ag + (long)r * K + k0 + (g << 3)),
          (__attribute__((address_space(3))) void*)(As + (c << 3)),
          16, 0, 0);
    }
#pragma unroll
    for (int jj = 0; jj < 4; ++jj) {
      const int c = (jj << 8) | t;
      const int r = c >> 3;
      const int g = (c & 7) ^ (r & 7);
      __builtin_amdgcn_global_load_lds(
          (const __attribute__((address_space(1))) void*)(
              Bg + (long)r * K + k0 + (g << 3)),
          (__attribute__((address_space(3))) void*)(Bs + (c << 3)),
          16, 0, 0);
    }
    __syncthreads();   // drains vmcnt: tile resident

    const short* Aw = As + wm * 64 * BK;
    const short* Bw = Bs + wn * 64 * BK;
#pragma unroll
    for (int s = 0; s < 2; ++s) {
      const int cs = c0 ^ (s << 5);
      short8 af[4], bf[4];
#pragma unroll
      for (int i = 0; i < 4; i++)
        af[i] = *(const short8*)(Aw + (i * 16 + l16) * BK + cs);
#pragma unroll
      for (int j = 0; j < 4; j++)
        bf[j] = *(const short8*)(Bw + (j * 16 + l16) * BK + cs);
#pragma unroll
      for (int i = 0; i < 4; i++)
#pragma unroll
        for (int j = 0; j < 4; j++)
          acc[i][j] = __builtin_amdgcn_mfma_f32_16x16x32_bf16(
              af[i], bf[j], acc[i][j], 0, 0, 0);
    }
    __syncthreads();   // protect LDS before next stage (single buffer)
  }

  // epilogue: C/D layout col=lane&15 (n), row=quad*4+reg (m)
  const int mbase = tileM + wm * 64;
  const int nbase = tileN + wn * 64;
#pragma unroll
  for (int i = 0; i < 4; i++) {
#pragma unroll
    for (int j = 0; j < 4; j++) {
      int n = nbase + j * 16 + l16;
      float bv = bias[n];
#pragma unroll
      for (int r = 0; r < 4; r++) {
        int m = mbase + i * 16 + quad * 4 + r;
        Y[(long)m * N + n] = acc[i][j][r] + bv;
      }
    }
  }
}

// ---- fallback (only if ws too small / odd shapes): correct but slow -------
__global__ void naive_kernel(const float* __restrict__ x,
                             const int* __restrict__ qw,
                             const float* __restrict__ sw,
                             const float* __restrict__ bias,
                             float* __restrict__ y,
                             int M, int N, int K, int G) {
  long idx = (long)blockIdx.x * blockDim.x + threadIdx.x;
  if (idx >= (long)M * N) return;
  int m = (int)(idx / N), n = (int)(idx % N);
  int ng = K / G;
  float acc = 0.f;
  for (int g = 0; g < ng; g++) {
    float s = sw[(long)n * ng + g];
    float part = 0.f;
    for (int k = g * G; k < (g + 1) * G; k++)
      part += x[(long)m * K + k] * (float)qw[(long)n * K + k];
    acc += part * s;
  }
  y[idx] = acc + bias[n];
}

extern "C" void kernel_launch(void* const* d_in, const int* in_sizes, int n_in,
                              void* d_out, int out_size, void* d_ws, size_t ws_size,
                              hipStream_t stream) {
  const float* x = (const float*)d_in[0];
  const int* qw = (const int*)d_in[1];
  const float* sw = (const float*)d_in[2];
  const float* bias = (const float*)d_in[3];
  float* y = (float*)d_out;

  const int N = in_sizes[3];
  const int K = in_sizes[1] / N;
  const int M = in_sizes[0] / K;
  const int ngroups = in_sizes[2] / N;
  const int G = K / ngroups;

  const long MK = (long)M * K;
  const long NK = (long)N * K;
  const size_t need = (size_t)(MK + NK) * sizeof(short);

  if (ws_size < need || (M % BM) || (N % BN) || (K % BK) || (G % 8)) {
    long total = (long)M * N;
    naive_kernel<<<(unsigned)((total + 255) / 256), 256, 0, stream>>>(
        x, qw, sw, bias, y, M, N, K, G);
    return;
  }

  short* xb = (short*)d_ws;
  short* wb = xb + MK;

  const int kc = K / 8;        // chunks per row
  const int gc = G / 8;        // chunks per group
  int kcshift = ((kc & (kc - 1)) == 0) ? __builtin_ctz((unsigned)kc) : -1;
  int gcshift = ((gc & (gc - 1)) == 0) ? __builtin_ctz((unsigned)gc) : -1;

  prep_x_kernel<<<2048, 256, 0, stream>>>(x, xb, MK / 8);
  prep_w_kernel<<<2048, 256, 0, stream>>>(qw, sw, wb, NK / 8,
                                          kc, kcshift, gc, gcshift, ngroups);

  dim3 grid((unsigned)(N / BN), (unsigned)(M / BM));
  gemm_bt_kernel<<<grid, 256, 0, stream>>>(xb, wb, bias, y, M, N, K);
}